// Round 5
// baseline (1836.807 us; speedup 1.0000x reference)
//
#include <hip/hip_runtime.h>
#include <hip/hip_bf16.h>

// LSTM (all-tanh gates), B=128, T=1024, IN=512, UNITS=128.
//   k_wt    : W -> Wt bf16 [n][k] transposed
//   k_ut    : U -> Ut f32 [col][k] transposed
//   k_gemm2 : xW = x @ W, 64x512 blocks, dbuf LDS A, launch_bounds(512,4)
//             so 2 WGs/CU co-reside and hide the per-iter barrier.
//   k_scan  : 64 WGs, TWO batch elements per WG, software-pipelined:
//             half2(t): read hB, gate A(t), MFMA B(t), barrier
//             half1(t+1): read hA, gate B(t), MFMA A(t+1), barrier
//             Gate VALU of one batch hides ds_read latency + MFMA tail of
//             the other. U resident in VGPRs as hi/lo bf16 B-fragments
//             (exact split product ~f32 accuracy). h LDS stride 160 shorts
//             -> conflict-free b128 reads.

#define UNITS 128
#define IN_DIM 512
#define BATCH 128
#define SEQ 1024
#define GATES 512
#define M_ROWS (BATCH * SEQ)

typedef __attribute__((ext_vector_type(8))) short short8;
typedef __attribute__((ext_vector_type(4))) float floatx4;

__device__ __forceinline__ unsigned short f2bf(float f) {
    unsigned int x = __builtin_bit_cast(unsigned int, f);
    unsigned int r = (x + 0x7fffu + ((x >> 16) & 1u)) >> 16; // RNE
    return (unsigned short)r;
}
__device__ __forceinline__ float bf2f(unsigned short u) {
    unsigned int x = ((unsigned int)u) << 16;
    return __builtin_bit_cast(float, x);
}
__device__ __forceinline__ unsigned int pack2(float lo, float hi) {
    return (unsigned int)f2bf(lo) | ((unsigned int)f2bf(hi) << 16);
}

// LDS-only barrier: drains lgkmcnt, lets global loads ride across.
__device__ __forceinline__ void lds_barrier() {
    asm volatile("s_waitcnt lgkmcnt(0)\n\ts_barrier" ::: "memory");
}

__device__ __forceinline__ float fast_tanh(float x) {
    float xc = fminf(12.0f, fmaxf(-12.0f, x));
    float e = __expf(2.0f * xc);
    return 1.0f - 2.0f * __builtin_amdgcn_rcpf(e + 1.0f);
}

#define MFMA_BF16(A_, B_, C_) \
    __builtin_amdgcn_mfma_f32_16x16x32_bf16(A_, B_, C_, 0, 0, 0)

// ---------------- W transpose + convert: Wt[n][k] = bf16(W[k][n]) ----------
__global__ void k_wt(const float* __restrict__ W, unsigned short* __restrict__ Wt) {
    int idx = blockIdx.x * 256 + threadIdx.x;
    int n = idx >> 9;
    int k = idx & 511;
    Wt[idx] = f2bf(W[k * 512 + n]);
}

// ---------------- U transpose: Ut[col][k] = U[k][col] (f32) ----------------
__global__ void k_ut(const float* __restrict__ U, float* __restrict__ Ut) {
    int idx = blockIdx.x * 256 + threadIdx.x; // 65536
    int col = idx >> 7;
    int k = idx & 127;
    Ut[idx] = U[k * 512 + col];
}

// ---------------- GEMM: C[m][n] = sum_k A[m][k] * W[k][n] ------------------
// Block = 64 rows x 512 cols, 512 threads (8 waves; wave w -> cols [64w,64w+64)).
// A staged via dbuf LDS (f32->bf16 repack); B direct L2->reg, depth-1.
template <bool XWF32>
__global__ void __launch_bounds__(512, 4)
k_gemm2(const float* __restrict__ A, const unsigned short* __restrict__ Bt,
        void* __restrict__ Cout) {
    __shared__ __align__(16) unsigned short As[2][64 * 40];
    const int tid = threadIdx.x;
    const int m0 = blockIdx.x << 6;
    const int l = tid & 63;
    const int w = tid >> 6;
    const int lrow = l & 15;
    const int lq = l >> 4;
    const int srow = tid >> 3;       // 64 rows, 8 threads/row
    const int scol = (tid & 7) << 2; // 4-float chunk
    const float* ap = A + (size_t)(m0 + srow) * 512 + scol;
    unsigned short* as = &As[0][srow * 40 + scol];
    const unsigned short* bp = Bt + (size_t)((w << 6) + lrow) * 512 + lq * 8;

    floatx4 acc[4][4] = {};
    float4 a_pf[2];
    a_pf[0] = *(const float4*)ap;
    a_pf[1] = *(const float4*)(ap + 32);
    short8 b_cur[4];
#pragma unroll
    for (int ni = 0; ni < 4; ++ni) b_cur[ni] = *(const short8*)(bp + ni * 8192);

#pragma unroll
    for (int it = 0; it < 16; ++it) {
        const int buf = it & 1;
        uint2 pa;
        pa.x = pack2(a_pf[buf].x, a_pf[buf].y);
        pa.y = pack2(a_pf[buf].z, a_pf[buf].w);
        *(uint2*)(as + buf * 2560) = pa;
        lds_barrier(); // As[buf] visible; prior readers of buf fenced at it-1
        if (it + 2 < 16) a_pf[buf] = *(const float4*)(ap + it * 32 + 64);
        short8 af[4];
#pragma unroll
        for (int mi = 0; mi < 4; ++mi)
            af[mi] = *(const short8*)&As[buf][(mi * 16 + lrow) * 40 + lq * 8];
#pragma unroll
        for (int mi = 0; mi < 4; ++mi)
#pragma unroll
            for (int ni = 0; ni < 4; ++ni)
                acc[mi][ni] = MFMA_BF16(af[mi], b_cur[ni], acc[mi][ni]);
        if (it + 1 < 16) {
#pragma unroll
            for (int ni = 0; ni < 4; ++ni)
                b_cur[ni] = *(const short8*)(bp + ni * 8192 + (it + 1) * 32);
        }
    }
    // epilogue: C/D layout col=lane&15, row=(lane>>4)*4+r
#pragma unroll
    for (int mi = 0; mi < 4; ++mi) {
#pragma unroll
        for (int ni = 0; ni < 4; ++ni) {
            int row = m0 + mi * 16 + lq * 4;
            int col = (w << 6) + ni * 16 + lrow;
            if (XWF32) {
                float* Cf = (float*)Cout;
#pragma unroll
                for (int r = 0; r < 4; ++r)
                    Cf[(size_t)(row + r) * 512 + col] = acc[mi][ni][r];
            } else {
                unsigned short* Cb = (unsigned short*)Cout;
#pragma unroll
                for (int r = 0; r < 4; ++r)
                    Cb[(size_t)(row + r) * 512 + col] = f2bf(acc[mi][ni][r]);
            }
        }
    }
}

// ---------------- recurrent scan: 2 batches per WG, pipelined --------------
// Gate phase for batch ZG (consumes zsum regs from its MFMA issued last half,
// refills its xw slot), then MFMA for batch RIDX into ZR. One lds barrier.
#define G_PHASE(ZG, XB, SLOT, CS, HS, GIDX, XPF, XPB, TNEXT)                   \
    {                                                                          \
        float zz0 = XB[SLOT][0] + b4[0] + ZG[0][0] + ZG[0][1];                 \
        float zz1 = XB[SLOT][1] + b4[1] + ZG[1][0] + ZG[1][1];                 \
        float zz2 = XB[SLOT][2] + b4[2] + ZG[2][0] + ZG[2][1];                 \
        float zz3 = XB[SLOT][3] + b4[3] + ZG[3][0] + ZG[3][1];                 \
        float gi_ = fast_tanh(zz0), gf_ = fast_tanh(zz1);                      \
        float gg_ = fast_tanh(zz2), go_ = fast_tanh(zz3);                      \
        CS = fmaf(gf_, CS, gi_ * gg_);                                         \
        HS = go_ * fast_tanh(CS);                                              \
        unsigned short hh = f2bf(HS);                                          \
        unsigned short hl2 = f2bf(HS - bf2f(hh));                              \
        if (l < 16) {                                                          \
            hL[GIDX][0][u16] = hh;                                             \
            hL[GIDX][1][u16] = hl2;                                            \
            if ((TNEXT) < SEQ) {                                               \
                _Pragma("unroll") for (int g = 0; g < 4; ++g)                  \
                    XB[SLOT][g] =                                              \
                        XWF32 ? XPF[(size_t)(TNEXT)*512 + g * 128]             \
                              : bf2f(XPB[(size_t)(TNEXT)*512 + g * 128]);      \
            }                                                                  \
        }                                                                      \
    }

#define HALF(RIDX, ZR, ZG, XB, SLOT, CS, HS, GIDX, XPF, XPB, TNEXT)            \
    {                                                                          \
        short8 af0 = *(const short8*)&hL[RIDX][n & 1][q * 8];                  \
        short8 af1 = *(const short8*)&hL[RIDX][n & 1][32 + q * 8];             \
        short8 af2 = *(const short8*)&hL[RIDX][n & 1][64 + q * 8];             \
        short8 af3 = *(const short8*)&hL[RIDX][n & 1][96 + q * 8];             \
        G_PHASE(ZG, XB, SLOT, CS, HS, GIDX, XPF, XPB, TNEXT);                  \
        _Pragma("unroll") for (int g = 0; g < 4; ++g) {                        \
            floatx4 a = {0.f, 0.f, 0.f, 0.f};                                  \
            a = MFMA_BF16(af0, Bhi[g][0], a);                                  \
            a = MFMA_BF16(af1, Bhi[g][1], a);                                  \
            a = MFMA_BF16(af2, Bhi[g][2], a);                                  \
            a = MFMA_BF16(af3, Bhi[g][3], a);                                  \
            a = MFMA_BF16(af0, Blo[g][0], a);                                  \
            a = MFMA_BF16(af1, Blo[g][1], a);                                  \
            a = MFMA_BF16(af2, Blo[g][2], a);                                  \
            a = MFMA_BF16(af3, Blo[g][3], a);                                  \
            ZR[g] = a;                                                         \
        }                                                                      \
        lds_barrier();                                                         \
    }

template <bool XWF32>
__global__ void __launch_bounds__(512, 2)
k_scan(const void* __restrict__ xwv, const float* __restrict__ Ut,
       const float* __restrict__ bias, float* __restrict__ out) {
    __shared__ __align__(16) unsigned short hL[2][2][160]; // [batch][hi/lo][pad160]
    const int tid = threadIdx.x;
    const int p = blockIdx.x; // batch pair
    const int l = tid & 63;
    const int w = tid >> 6;
    const int n = l & 15;
    const int q = l >> 4;
    const int u16 = (w << 4) + n;
    const int bA = 2 * p, bB = 2 * p + 1;

    // U as B-operand fragments (hi/lo split), resident ~128 VGPRs, shared by
    // both batches.
    short8 Bhi[4][4], Blo[4][4];
#pragma unroll
    for (int g = 0; g < 4; ++g) {
        const float* up = Ut + (g * 128 + u16) * 128 + q * 8;
#pragma unroll
        for (int c = 0; c < 4; ++c) {
            float4 v0 = *(const float4*)(up + c * 32);
            float4 v1 = *(const float4*)(up + c * 32 + 4);
            float vv[8] = {v0.x, v0.y, v0.z, v0.w, v1.x, v1.y, v1.z, v1.w};
            short8 hi, lo;
#pragma unroll
            for (int j = 0; j < 8; ++j) {
                unsigned short hb = f2bf(vv[j]);
                hi[j] = (short)hb;
                lo[j] = (short)f2bf(vv[j] - bf2f(hb));
            }
            Bhi[g][c] = hi;
            Blo[g][c] = lo;
        }
    }

    if (tid < 320) ((unsigned int*)hL)[tid] = 0u; // h=0 both batches

    float b4[4];
#pragma unroll
    for (int g = 0; g < 4; ++g) b4[g] = bias[g * 128 + u16];

    const float* xpfA = (const float*)xwv + (size_t)bA * SEQ * 512 + u16;
    const float* xpfB = (const float*)xwv + (size_t)bB * SEQ * 512 + u16;
    const unsigned short* xpbA =
        (const unsigned short*)xwv + (size_t)bA * SEQ * 512 + u16;
    const unsigned short* xpbB =
        (const unsigned short*)xwv + (size_t)bB * SEQ * 512 + u16;

    float xbA[2][4], xbB[2][4];
    if (l < 16) {
#pragma unroll
        for (int s = 0; s < 2; ++s)
#pragma unroll
            for (int g = 0; g < 4; ++g) {
                xbA[s][g] = XWF32 ? xpfA[(size_t)s * 512 + g * 128]
                                  : bf2f(xpbA[(size_t)s * 512 + g * 128]);
                xbB[s][g] = XWF32 ? xpfB[(size_t)s * 512 + g * 128]
                                  : bf2f(xpbB[(size_t)s * 512 + g * 128]);
            }
    }

    float cA = 0.f, hA = 0.f, cB = 0.f, hB = 0.f;
    floatx4 zsA[4], zsB[4];
    lds_barrier(); // h zero visible

    { // prologue: MFMA A(0) from hA=0
        short8 af0 = *(const short8*)&hL[0][n & 1][q * 8];
        short8 af1 = *(const short8*)&hL[0][n & 1][32 + q * 8];
        short8 af2 = *(const short8*)&hL[0][n & 1][64 + q * 8];
        short8 af3 = *(const short8*)&hL[0][n & 1][96 + q * 8];
#pragma unroll
        for (int g = 0; g < 4; ++g) {
            floatx4 a = {0.f, 0.f, 0.f, 0.f};
            a = MFMA_BF16(af0, Bhi[g][0], a);
            a = MFMA_BF16(af1, Bhi[g][1], a);
            a = MFMA_BF16(af2, Bhi[g][2], a);
            a = MFMA_BF16(af3, Bhi[g][3], a);
            a = MFMA_BF16(af0, Blo[g][0], a);
            a = MFMA_BF16(af1, Blo[g][1], a);
            a = MFMA_BF16(af2, Blo[g][2], a);
            a = MFMA_BF16(af3, Blo[g][3], a);
            zsA[g] = a;
        }
    }
    lds_barrier(); // prologue readers of hL[0] done before G(A,0) writes

#pragma unroll 1
    for (int t = 0; t < SEQ; t += 2) {
        // half2(t): read hB(t-1)->MFMA B(t); gate A(t)
        HALF(1, zsB, zsA, xbA, 0, cA, hA, 0, xpfA, xpbA, t + 2)
        // half1(t+1): read hA(t)->MFMA A(t+1); gate B(t)
        HALF(0, zsA, zsB, xbB, 0, cB, hB, 1, xpfB, xpbB, t + 2)
        // half2(t+1)
        HALF(1, zsB, zsA, xbA, 1, cA, hA, 0, xpfA, xpbA, t + 3)
        // half1(t+2) (at t=SEQ-2 the MFMA A(SEQ) result is unused -- harmless)
        HALF(0, zsA, zsB, xbB, 1, cB, hB, 1, xpfB, xpbB, t + 3)
    }

    if (l < 16) {
        out[bA * UNITS + u16] = hA;
        out[bB * UNITS + u16] = hB;
    }
}

// ---------------------------------------------------------------------------
extern "C" void kernel_launch(void* const* d_in, const int* in_sizes, int n_in,
                              void* d_out, int out_size, void* d_ws, size_t ws_size,
                              hipStream_t stream) {
    const float* x = (const float*)d_in[0]; // [128,1024,512]
    const float* W = (const float*)d_in[1]; // [512,512]
    const float* U = (const float*)d_in[2]; // [128,512]
    const float* b = (const float*)d_in[3]; // [512]
    float* out = (float*)d_out;             // [128,128]

    char* ws = (char*)d_ws;
    unsigned short* Wt = (unsigned short*)ws; // 512 KB
    float* Ut = (float*)(ws + 524288);        // 256 KB
    char* rest = ws + 524288 + 262144;
    const size_t base = 524288 + 262144;
    const size_t XW_F32 = (size_t)M_ROWS * 512 * 4; // 256 MB

    k_wt<<<dim3(1024), dim3(256), 0, stream>>>(W, Wt);
    k_ut<<<dim3(256), dim3(256), 0, stream>>>(U, Ut);

    dim3 ggrid(M_ROWS / 64); // 2048 blocks
    if (ws_size >= base + XW_F32) {
        float* xw = (float*)rest;
        k_gemm2<true><<<ggrid, dim3(512), 0, stream>>>(x, Wt, xw);
        k_scan<true><<<dim3(64), dim3(512), 0, stream>>>(xw, Ut, b, out);
    } else {
        unsigned short* xw = (unsigned short*)rest;
        k_gemm2<false><<<ggrid, dim3(512), 0, stream>>>(x, Wt, xw);
        k_scan<false><<<dim3(64), dim3(512), 0, stream>>>(xw, Ut, b, out);
    }
}